// Round 1
// baseline (1256.810 us; speedup 1.0000x reference)
//
#include <hip/hip_runtime.h>
#include <math.h>

#define NTOK 320
#define BB   64
#define DIMC 512
#define HIDC 256
#define NHEAD 8

#define F_BIAS 1
#define F_RELU 2
#define F_RES1 4
#define F_RES2 8

// C[b][j,n] = epilogue( sum_d W[d*ldw + j] * X[b][d,n] )
// 64x64 output tile, 32-deep K tiles, 256 threads, 4x4 micro-tile/thread.
template<int FLAGS>
__global__ __launch_bounds__(256)
void gemm_wtx(const float* __restrict__ W, int ldw,
              const float* __restrict__ X, long sX,
              float* __restrict__ C, long sC,
              int Dk,
              const float* __restrict__ bias,
              const float* __restrict__ R1, long sR1,
              const float* __restrict__ R2, long sR2)
{
    const int b  = blockIdx.z;
    const int j0 = blockIdx.x << 6;
    const int n0 = blockIdx.y << 6;
    const float* Xb = X + (long)b * sX;

    __shared__ float Ws[32][64];
    __shared__ float Xs[32][64];

    const int t  = threadIdx.x;
    const int tn = t & 15;   // -> n micro-tile (n0 + tn*4 .. +3)
    const int tj = t >> 4;   // -> j micro-tile (j0 + tj*4 .. +3)

    float acc[4][4] = {{0.f,0.f,0.f,0.f},{0.f,0.f,0.f,0.f},
                       {0.f,0.f,0.f,0.f},{0.f,0.f,0.f,0.f}};

    for (int d0 = 0; d0 < Dk; d0 += 32) {
        #pragma unroll
        for (int i = 0; i < 2; ++i) {
            const int l   = t + (i << 8);     // 0..511 float4 slots
            const int row = l >> 4;           // 0..31
            const int col = (l & 15) << 2;    // 0..60
            *(float4*)&Ws[row][col] = *(const float4*)&W[(long)(d0 + row) * ldw + j0 + col];
            *(float4*)&Xs[row][col] = *(const float4*)&Xb[(long)(d0 + row) * NTOK + n0 + col];
        }
        __syncthreads();
        #pragma unroll 8
        for (int dd = 0; dd < 32; ++dd) {
            const float4 wv = *(const float4*)&Ws[dd][tj << 2];
            const float4 xv = *(const float4*)&Xs[dd][tn << 2];
            const float wr[4] = {wv.x, wv.y, wv.z, wv.w};
            const float xr[4] = {xv.x, xv.y, xv.z, xv.w};
            #pragma unroll
            for (int i = 0; i < 4; ++i)
                #pragma unroll
                for (int k = 0; k < 4; ++k)
                    acc[i][k] = fmaf(wr[i], xr[k], acc[i][k]);
        }
        __syncthreads();
    }

    float* Cb = C + (long)b * sC;
    const int n = n0 + (tn << 2);
    #pragma unroll
    for (int i = 0; i < 4; ++i) {
        const int j = j0 + (tj << 2) + i;
        float4 v = make_float4(acc[i][0], acc[i][1], acc[i][2], acc[i][3]);
        if (FLAGS & F_BIAS) {
            const float bv = bias[j];
            v.x += bv; v.y += bv; v.z += bv; v.w += bv;
        }
        if (FLAGS & F_RES1) {
            const float4 r = *(const float4*)&R1[(long)b * sR1 + (long)j * NTOK + n];
            v.x += r.x; v.y += r.y; v.z += r.z; v.w += r.w;
        }
        if (FLAGS & F_RES2) {
            const float4 r = *(const float4*)&R2[(long)b * sR2 + (long)j * NTOK + n];
            v.x += r.x; v.y += r.y; v.z += r.z; v.w += r.w;
        }
        if (FLAGS & F_RELU) {
            v.x = fmaxf(v.x, 0.f); v.y = fmaxf(v.y, 0.f);
            v.z = fmaxf(v.z, 0.f); v.w = fmaxf(v.w, 0.f);
        }
        *(float4*)&Cb[(long)j * NTOK + n] = v;
    }
}

// Transpose the four 256x256 projection weights (einsum 'oc,bcn->bon' needs W[o][c] -> WT[c][o]).
__global__ __launch_bounds__(256)
void transpose4_k(const float* __restrict__ Wq, const float* __restrict__ Wk,
                  const float* __restrict__ Wv, const float* __restrict__ Wo,
                  float* __restrict__ out)
{
    __shared__ float tile[32][33];
    const float* src = (blockIdx.z == 0) ? Wq : (blockIdx.z == 1) ? Wk
                     : (blockIdx.z == 2) ? Wv : Wo;
    float* dst = out + (long)blockIdx.z * 65536;
    const int x0 = blockIdx.x << 5, y0 = blockIdx.y << 5;
    const int tx = threadIdx.x & 31, ty = threadIdx.x >> 5;  // 32 x 8
    for (int i = ty; i < 32; i += 8)
        tile[i][tx] = src[(long)(y0 + i) * 256 + x0 + tx];
    __syncthreads();
    for (int i = ty; i < 32; i += 8)
        dst[(long)(x0 + i) * 256 + y0 + tx] = tile[tx][i];
}

// One block per (slice, head, batch). Channel attention: 32x32 logits per head,
// contraction over Nt tokens; l2norm of q,k rows over tokens; softmax over d.
__global__ __launch_bounds__(256)
void attn_kernel(const float* __restrict__ Q, const float* __restrict__ K,
                 const float* __restrict__ V, float* __restrict__ O,
                 const float* __restrict__ temp)
{
    const int slice = blockIdx.x;
    const int h     = blockIdx.y;
    const int b     = blockIdx.z;
    const int n0    = slice ? 64 : 0;
    const int Nt    = slice ? 256 : 64;

    __shared__ float qs[32][260], ks[32][260], vs[32][260];
    __shared__ float P[32][36];
    __shared__ float invq[32], invk[32];

    const long base = (long)b * HIDC * NTOK + (long)h * 32 * NTOK + n0;
    const int t = threadIdx.x;
    const int nf4 = Nt >> 2;

    for (int idx = t; idx < 32 * nf4; idx += 256) {
        const int r  = idx / nf4;
        const int n4 = (idx % nf4) << 2;
        *(float4*)&qs[r][n4] = *(const float4*)&Q[base + (long)r * NTOK + n4];
        *(float4*)&ks[r][n4] = *(const float4*)&K[base + (long)r * NTOK + n4];
        *(float4*)&vs[r][n4] = *(const float4*)&V[base + (long)r * NTOK + n4];
    }
    __syncthreads();

    {   // row l2 norms over tokens (8 lanes per row)
        const int r = t >> 3, l8 = t & 7;
        float sq = 0.f, sk = 0.f;
        for (int k4 = l8; k4 < nf4; k4 += 8) {
            const float4 a = *(const float4*)&qs[r][k4 << 2];
            sq = fmaf(a.x,a.x, fmaf(a.y,a.y, fmaf(a.z,a.z, fmaf(a.w,a.w, sq))));
            const float4 c = *(const float4*)&ks[r][k4 << 2];
            sk = fmaf(c.x,c.x, fmaf(c.y,c.y, fmaf(c.z,c.z, fmaf(c.w,c.w, sk))));
        }
        sq += __shfl_xor(sq, 1); sq += __shfl_xor(sq, 2); sq += __shfl_xor(sq, 4);
        sk += __shfl_xor(sk, 1); sk += __shfl_xor(sk, 2); sk += __shfl_xor(sk, 4);
        if (l8 == 0) {
            invq[r] = 1.f / fmaxf(sqrtf(sq), 1e-12f);
            invk[r] = 1.f / fmaxf(sqrtf(sk), 1e-12f);
        }
    }
    __syncthreads();

    {   // logits + softmax: thread owns row c = t>>3, 4 cols db..db+3
        const int c = t >> 3, db = (t & 7) << 2;
        float s0 = 0.f, s1 = 0.f, s2 = 0.f, s3 = 0.f;
        for (int n = 0; n < Nt; n += 4) {
            const float4 qv = *(const float4*)&qs[c][n];
            const float4 k0 = *(const float4*)&ks[db + 0][n];
            const float4 k1 = *(const float4*)&ks[db + 1][n];
            const float4 k2 = *(const float4*)&ks[db + 2][n];
            const float4 k3 = *(const float4*)&ks[db + 3][n];
            s0 = fmaf(qv.x,k0.x, fmaf(qv.y,k0.y, fmaf(qv.z,k0.z, fmaf(qv.w,k0.w, s0))));
            s1 = fmaf(qv.x,k1.x, fmaf(qv.y,k1.y, fmaf(qv.z,k1.z, fmaf(qv.w,k1.w, s1))));
            s2 = fmaf(qv.x,k2.x, fmaf(qv.y,k2.y, fmaf(qv.z,k2.z, fmaf(qv.w,k2.w, s2))));
            s3 = fmaf(qv.x,k3.x, fmaf(qv.y,k3.y, fmaf(qv.z,k3.z, fmaf(qv.w,k3.w, s3))));
        }
        const float sc = invq[c] * temp[h];
        float l0 = s0 * sc * invk[db + 0];
        float l1 = s1 * sc * invk[db + 1];
        float l2 = s2 * sc * invk[db + 2];
        float l3 = s3 * sc * invk[db + 3];
        float m = fmaxf(fmaxf(l0, l1), fmaxf(l2, l3));
        m = fmaxf(m, __shfl_xor(m, 1));
        m = fmaxf(m, __shfl_xor(m, 2));
        m = fmaxf(m, __shfl_xor(m, 4));
        const float e0 = expf(l0 - m), e1 = expf(l1 - m);
        const float e2 = expf(l2 - m), e3 = expf(l3 - m);
        float sum = e0 + e1 + e2 + e3;
        sum += __shfl_xor(sum, 1); sum += __shfl_xor(sum, 2); sum += __shfl_xor(sum, 4);
        const float inv = 1.f / sum;
        P[c][db + 0] = e0 * inv; P[c][db + 1] = e1 * inv;
        P[c][db + 2] = e2 * inv; P[c][db + 3] = e3 * inv;
    }
    __syncthreads();

    for (int idx = t; idx < 32 * nf4; idx += 256) {   // out = P @ v
        const int c  = idx / nf4;
        const int n4 = (idx % nf4) << 2;
        float4 o = make_float4(0.f, 0.f, 0.f, 0.f);
        #pragma unroll
        for (int d = 0; d < 32; ++d) {
            const float p = P[c][d];
            const float4 vv = *(const float4*)&vs[d][n4];
            o.x = fmaf(p, vv.x, o.x); o.y = fmaf(p, vv.y, o.y);
            o.z = fmaf(p, vv.z, o.z); o.w = fmaf(p, vv.w, o.w);
        }
        *(float4*)&O[base + (long)c * NTOK + n4] = o;
    }
}

// LayerNorm over the 512 channels per token; Pre/out are (B,512,320) channel-major.
__global__ __launch_bounds__(256)
void ln_kernel(const float* __restrict__ Pre, const float* __restrict__ gamma,
               const float* __restrict__ beta, float* __restrict__ out)
{
    const int b  = blockIdx.y;
    const int n  = (blockIdx.x << 6) + (threadIdx.x & 63);
    const int q  = threadIdx.x >> 6;   // 0..3
    const float* Pb = Pre + (long)b * DIMC * NTOK;
    float s = 0.f, s2 = 0.f;
    for (int d = q; d < DIMC; d += 4) {
        const float v = Pb[(long)d * NTOK + n];
        s += v; s2 = fmaf(v, v, s2);
    }
    __shared__ float sb[4][64], s2b[4][64];
    sb[q][threadIdx.x & 63] = s;
    s2b[q][threadIdx.x & 63] = s2;
    __syncthreads();
    float ts = 0.f, ts2 = 0.f;
    #pragma unroll
    for (int i = 0; i < 4; ++i) { ts += sb[i][threadIdx.x & 63]; ts2 += s2b[i][threadIdx.x & 63]; }
    const float mu   = ts * (1.f / 512.f);
    const float var  = ts2 * (1.f / 512.f) - mu * mu;
    const float rstd = 1.f / sqrtf(var + 1e-5f);
    float* Ob = out + (long)b * DIMC * NTOK;
    for (int d = q; d < DIMC; d += 4) {
        const float v = Pb[(long)d * NTOK + n];
        Ob[(long)d * NTOK + n] = (v - mu) * rstd * gamma[d] + beta[d];
    }
}

extern "C" void kernel_launch(void* const* d_in, const int* in_sizes, int n_in,
                              void* d_out, int out_size, void* d_ws, size_t ws_size,
                              hipStream_t stream)
{
    const float* x1     = (const float*)d_in[0];
    const float* x2     = (const float*)d_in[1];
    const float* W_lin  = (const float*)d_in[2];
    const float* b_lin  = (const float*)d_in[3];
    const float* W_down = (const float*)d_in[4];
    const float* b_down = (const float*)d_in[5];
    const float* W_up   = (const float*)d_in[6];
    const float* b_up   = (const float*)d_in[7];
    const float* Wq     = (const float*)d_in[8];
    const float* Wk     = (const float*)d_in[9];
    const float* Wv     = (const float*)d_in[10];
    const float* Wo     = (const float*)d_in[11];
    const float* temp   = (const float*)d_in[12];
    const float* W_end  = (const float*)d_in[13];
    const float* b_end  = (const float*)d_in[14];
    const float* gamma  = (const float*)d_in[15];
    const float* beta   = (const float*)d_in[16];

    float* ws = (float*)d_ws;
    const long s512  = (long)DIMC * NTOK;      // 163840
    const long s1024 = 2L * s512;
    const long s256  = (long)HIDC * NTOK;      // 81920

    float* H1  = ws;                               // B x 1024 x 320  (rows 0-511 = Y1, 512-1023 = U1)
    float* U2  = H1 + (long)BB * 1024 * NTOK;      // B x 512 x 320
    float* XB  = U2 + (long)BB * 512 * NTOK;       // B x 256 x 320
    float* YB  = XB + (long)BB * 256 * NTOK;
    float* Qb  = YB + (long)BB * 256 * NTOK;
    float* Kb  = Qb + (long)BB * 256 * NTOK;
    float* Vb  = Kb + (long)BB * 256 * NTOK;
    float* WT  = Vb + (long)BB * 256 * NTOK;       // 4 x 256 x 256 transposed proj weights
    float* Y1   = H1;                // stride s1024
    float* U1   = H1 + 512 * NTOK;   // stride s1024
    float* AO   = YB;                // alias: YB dead after Q projection
    float* OUTC = Qb;                // alias: Q dead after attention
    float* PRE  = U2;                // alias: U2 dead after YB projection

    const dim3 blk(256);

    transpose4_k<<<dim3(8, 8, 4), blk, 0, stream>>>(Wq, Wk, Wv, Wo, WT);

    // H1 = relu(W_lin^T @ X1 + b_lin)            (Y1 | U1)
    gemm_wtx<F_BIAS | F_RELU><<<dim3(16, 5, BB), blk, 0, stream>>>(
        W_lin, 1024, x1, s512, H1, s1024, 512, b_lin, nullptr, 0, nullptr, 0);
    // U2 = relu(W_lin[:,512:]^T @ X2 + b_lin[512:])
    gemm_wtx<F_BIAS | F_RELU><<<dim3(8, 5, BB), blk, 0, stream>>>(
        W_lin + 512, 1024, x2, s512, U2, s512, 512, b_lin + 512, nullptr, 0, nullptr, 0);
    // XB = relu(W_down^T @ U1 + b_down)   (== xb, the res1)
    gemm_wtx<F_BIAS | F_RELU><<<dim3(4, 5, BB), blk, 0, stream>>>(
        W_down, 256, U1, s1024, XB, s256, 512, b_down, nullptr, 0, nullptr, 0);
    // YB = relu(W_down^T @ U2 + b_down)   (== yb)
    gemm_wtx<F_BIAS | F_RELU><<<dim3(4, 5, BB), blk, 0, stream>>>(
        W_down, 256, U2, s512, YB, s256, 512, b_down, nullptr, 0, nullptr, 0);
    // Q = Wq @ YB ; K = Wk @ XB ; V = Wv @ XB   (via transposed weights)
    gemm_wtx<0><<<dim3(4, 5, BB), blk, 0, stream>>>(
        WT + 0 * 65536, 256, YB, s256, Qb, s256, 256, nullptr, nullptr, 0, nullptr, 0);
    gemm_wtx<0><<<dim3(4, 5, BB), blk, 0, stream>>>(
        WT + 1 * 65536, 256, XB, s256, Kb, s256, 256, nullptr, nullptr, 0, nullptr, 0);
    gemm_wtx<0><<<dim3(4, 5, BB), blk, 0, stream>>>(
        WT + 2 * 65536, 256, XB, s256, Vb, s256, 256, nullptr, nullptr, 0, nullptr, 0);
    // attention per (slice, head, batch) -> AO
    attn_kernel<<<dim3(2, NHEAD, BB), blk, 0, stream>>>(Qb, Kb, Vb, AO, temp);
    // OUTC = Wo @ AO + XB   (res1)
    gemm_wtx<F_RES1><<<dim3(4, 5, BB), blk, 0, stream>>>(
        WT + 3 * 65536, 256, AO, s256, OUTC, s256, 256, nullptr, XB, s256, nullptr, 0);
    // Y1 <- Y1 + U1 + W_up^T @ OUTC + b_up      (= y1 + branch outputs)
    gemm_wtx<F_BIAS | F_RES1 | F_RES2><<<dim3(8, 5, BB), blk, 0, stream>>>(
        W_up, 512, OUTC, s256, Y1, s1024, 256, b_up, U1, s1024, Y1, s1024);
    // PRE = x1 + W_end^T @ Y1 + b_end
    gemm_wtx<F_BIAS | F_RES1><<<dim3(8, 5, BB), blk, 0, stream>>>(
        W_end, 512, Y1, s1024, PRE, s512, 512, b_end, x1, s512, nullptr, 0);
    // LayerNorm over channels -> d_out (already channel-major == output layout)
    ln_kernel<<<dim3(5, BB), blk, 0, stream>>>(PRE, gamma, beta, (float*)d_out);
}

// Round 4
// 648.738 us; speedup vs baseline: 1.9373x; 1.9373x over previous
//
#include <hip/hip_runtime.h>
#include <math.h>

#define NTOK 320
#define BB   64
#define DIMC 512
#define HIDC 256
#define NHEAD 8

#define F_BIAS 1
#define F_RELU 2
#define F_RES1 4
#define F_RES2 8

#define BM 128
#define BN 64
#define BK 32

typedef __attribute__((ext_vector_type(8))) short bf8_t;   // 8 bf16 (4 VGPRs)
typedef __attribute__((ext_vector_type(4))) float f4_t;

// truncate-split: f = hi + lo with hi,lo representable in bf16
__device__ __forceinline__ void bsplit(float f, short& h, short& l) {
    const unsigned u = __float_as_uint(f);
    h = (short)(u >> 16);
    const float fh = __uint_as_float(u & 0xffff0000u);
    const float fl = f - fh;                   // exact in fp32
    l = (short)(__float_as_uint(fl) >> 16);
}

// C[b][j,n] = epi( sum_d W[d*ldw + j] * X[b][d,n] ), fp32 via bf16x3 MFMA.
// 128x64 tile, K-slabs of 32, 256 threads (4 waves, 2x2), wave-tile 64x32.
template<int FLAGS>
__global__ __launch_bounds__(256)
void gemm_mfma(const float* __restrict__ W, int ldw,
               const float* __restrict__ X, long sX,
               float* __restrict__ C, long sC,
               int Dk,
               const float* __restrict__ bias,
               const float* __restrict__ R1, long sR1,
               const float* __restrict__ R2, long sR2)
{
    __shared__ float Ws[BK][BM];   // [k][m], granule-swizzled:  c' = c ^ ((k>>3)<<2)
    __shared__ float Xs[BK][BN];   // [k][n], same swizzle

    const int b  = blockIdx.z;
    const int j0 = blockIdx.x * BM;
    const int n0 = blockIdx.y * BN;
    const float* Xb = X + (long)b * sX;

    const int t    = threadIdx.x;
    const int wave = t >> 6;
    const int lane = t & 63;
    const int wm   = wave >> 1;     // 0..1 -> m-half (64 rows)
    const int wn   = wave & 1;      // 0..1 -> n-half (32 cols)
    const int r16  = lane & 15;
    const int g    = lane >> 4;     // k-group 0..3

    f4_t acc[4][2];
    #pragma unroll
    for (int i = 0; i < 4; ++i)
        #pragma unroll
        for (int j = 0; j < 2; ++j)
            acc[i][j] = (f4_t){0.f, 0.f, 0.f, 0.f};

    for (int d0 = 0; d0 < Dk; d0 += BK) {
        // ---- stage W slab: 32 x 128 fp32 (1024 float4 slots) ----
        #pragma unroll
        for (int i = 0; i < 4; ++i) {
            const int slot = t + (i << 8);
            const int k = slot >> 5;          // 0..31
            const int c = slot & 31;          // float4 granule
            const f4_t v = *(const f4_t*)&W[(long)(d0 + k) * ldw + j0 + (c << 2)];
            const int cs = c ^ ((k >> 3) << 2);
            *(f4_t*)&Ws[k][cs << 2] = v;
        }
        // ---- stage X slab: 32 x 64 fp32 (512 float4 slots) ----
        #pragma unroll
        for (int i = 0; i < 2; ++i) {
            const int slot = t + (i << 8);
            const int k = slot >> 4;          // 0..31
            const int c = slot & 15;
            const f4_t v = *(const f4_t*)&Xb[(long)(d0 + k) * NTOK + n0 + (c << 2)];
            const int cs = c ^ ((k >> 3) << 2);
            *(f4_t*)&Xs[k][cs << 2] = v;
        }
        __syncthreads();

        // ---- build fragments (column reads, swizzle-matched) ----
        bf8_t ah[4], al[4], bh[2], bl[2];
        #pragma unroll
        for (int fm = 0; fm < 4; ++fm) {
            const int m  = wm * 64 + fm * 16 + r16;
            const int col = (((m >> 2) ^ (g << 2)) << 2) | (m & 3);
            #pragma unroll
            for (int e = 0; e < 8; ++e) {
                short h, l;
                bsplit(Ws[g * 8 + e][col], h, l);
                ah[fm][e] = h; al[fm][e] = l;
            }
        }
        #pragma unroll
        for (int fn = 0; fn < 2; ++fn) {
            const int n  = wn * 32 + fn * 16 + r16;
            const int col = (((n >> 2) ^ (g << 2)) << 2) | (n & 3);
            #pragma unroll
            for (int e = 0; e < 8; ++e) {
                short h, l;
                bsplit(Xs[g * 8 + e][col], h, l);
                bh[fn][e] = h; bl[fn][e] = l;
            }
        }

        // ---- bf16x3 MFMA: D += Ah*Bh + Ah*Bl + Al*Bh ----
        #pragma unroll
        for (int fm = 0; fm < 4; ++fm)
            #pragma unroll
            for (int fn = 0; fn < 2; ++fn) {
                acc[fm][fn] = __builtin_amdgcn_mfma_f32_16x16x32_bf16(ah[fm], bh[fn], acc[fm][fn], 0, 0, 0);
                acc[fm][fn] = __builtin_amdgcn_mfma_f32_16x16x32_bf16(ah[fm], bl[fn], acc[fm][fn], 0, 0, 0);
                acc[fm][fn] = __builtin_amdgcn_mfma_f32_16x16x32_bf16(al[fm], bh[fn], acc[fm][fn], 0, 0, 0);
            }
        __syncthreads();
    }

    // ---- epilogue:  D row = g*4 + reg, col = r16 within fragment ----
    float* Cb = C + (long)b * sC;
    #pragma unroll
    for (int fm = 0; fm < 4; ++fm) {
        #pragma unroll
        for (int reg = 0; reg < 4; ++reg) {
            const int m = j0 + wm * 64 + fm * 16 + g * 4 + reg;
            float bv = 0.f;
            if (FLAGS & F_BIAS) bv = bias[m];
            #pragma unroll
            for (int fn = 0; fn < 2; ++fn) {
                const int n = n0 + wn * 32 + fn * 16 + r16;
                float v = acc[fm][fn][reg] + bv;
                if (FLAGS & F_RES1) v += R1[(long)b * sR1 + (long)m * NTOK + n];
                if (FLAGS & F_RES2) v += R2[(long)b * sR2 + (long)m * NTOK + n];
                if (FLAGS & F_RELU) v = fmaxf(v, 0.f);
                Cb[(long)m * NTOK + n] = v;
            }
        }
    }
}

// Transpose the four 256x256 projection weights ('oc,bcn->bon' needs W[o][c] -> WT[c][o]).
__global__ __launch_bounds__(256)
void transpose4_k(const float* __restrict__ Wq, const float* __restrict__ Wk,
                  const float* __restrict__ Wv, const float* __restrict__ Wo,
                  float* __restrict__ out)
{
    __shared__ float tile[32][33];
    const float* src = (blockIdx.z == 0) ? Wq : (blockIdx.z == 1) ? Wk
                     : (blockIdx.z == 2) ? Wv : Wo;
    float* dst = out + (long)blockIdx.z * 65536;
    const int x0 = blockIdx.x << 5, y0 = blockIdx.y << 5;
    const int tx = threadIdx.x & 31, ty = threadIdx.x >> 5;  // 32 x 8
    for (int i = ty; i < 32; i += 8)
        tile[i][tx] = src[(long)(y0 + i) * 256 + x0 + tx];
    __syncthreads();
    for (int i = ty; i < 32; i += 8)
        dst[(long)(x0 + i) * 256 + y0 + tx] = tile[tx][i];
}

// One block per (slice, head, batch). Channel attention: 32x32 logits per head,
// contraction over Nt tokens; l2norm of q,k rows over tokens; softmax over d.
__global__ __launch_bounds__(256)
void attn_kernel(const float* __restrict__ Q, const float* __restrict__ K,
                 const float* __restrict__ V, float* __restrict__ O,
                 const float* __restrict__ temp)
{
    const int slice = blockIdx.x;
    const int h     = blockIdx.y;
    const int b     = blockIdx.z;
    const int n0    = slice ? 64 : 0;
    const int Nt    = slice ? 256 : 64;

    __shared__ float qs[32][260], ks[32][260], vs[32][260];
    __shared__ float P[32][36];
    __shared__ float invq[32], invk[32];

    const long base = (long)b * HIDC * NTOK + (long)h * 32 * NTOK + n0;
    const int t = threadIdx.x;
    const int nf4 = Nt >> 2;

    for (int idx = t; idx < 32 * nf4; idx += 256) {
        const int r  = idx / nf4;
        const int n4 = (idx % nf4) << 2;
        *(float4*)&qs[r][n4] = *(const float4*)&Q[base + (long)r * NTOK + n4];
        *(float4*)&ks[r][n4] = *(const float4*)&K[base + (long)r * NTOK + n4];
        *(float4*)&vs[r][n4] = *(const float4*)&V[base + (long)r * NTOK + n4];
    }
    __syncthreads();

    {   // row l2 norms over tokens (8 lanes per row)
        const int r = t >> 3, l8 = t & 7;
        float sq = 0.f, sk = 0.f;
        for (int k4 = l8; k4 < nf4; k4 += 8) {
            const float4 a = *(const float4*)&qs[r][k4 << 2];
            sq = fmaf(a.x,a.x, fmaf(a.y,a.y, fmaf(a.z,a.z, fmaf(a.w,a.w, sq))));
            const float4 c = *(const float4*)&ks[r][k4 << 2];
            sk = fmaf(c.x,c.x, fmaf(c.y,c.y, fmaf(c.z,c.z, fmaf(c.w,c.w, sk))));
        }
        sq += __shfl_xor(sq, 1); sq += __shfl_xor(sq, 2); sq += __shfl_xor(sq, 4);
        sk += __shfl_xor(sk, 1); sk += __shfl_xor(sk, 2); sk += __shfl_xor(sk, 4);
        if (l8 == 0) {
            invq[r] = 1.f / fmaxf(sqrtf(sq), 1e-12f);
            invk[r] = 1.f / fmaxf(sqrtf(sk), 1e-12f);
        }
    }
    __syncthreads();

    {   // logits + softmax: thread owns row c = t>>3, 4 cols db..db+3
        const int c = t >> 3, db = (t & 7) << 2;
        float s0 = 0.f, s1 = 0.f, s2 = 0.f, s3 = 0.f;
        for (int n = 0; n < Nt; n += 4) {
            const float4 qv = *(const float4*)&qs[c][n];
            const float4 k0 = *(const float4*)&ks[db + 0][n];
            const float4 k1 = *(const float4*)&ks[db + 1][n];
            const float4 k2 = *(const float4*)&ks[db + 2][n];
            const float4 k3 = *(const float4*)&ks[db + 3][n];
            s0 = fmaf(qv.x,k0.x, fmaf(qv.y,k0.y, fmaf(qv.z,k0.z, fmaf(qv.w,k0.w, s0))));
            s1 = fmaf(qv.x,k1.x, fmaf(qv.y,k1.y, fmaf(qv.z,k1.z, fmaf(qv.w,k1.w, s1))));
            s2 = fmaf(qv.x,k2.x, fmaf(qv.y,k2.y, fmaf(qv.z,k2.z, fmaf(qv.w,k2.w, s2))));
            s3 = fmaf(qv.x,k3.x, fmaf(qv.y,k3.y, fmaf(qv.z,k3.z, fmaf(qv.w,k3.w, s3))));
        }
        const float sc = invq[c] * temp[h];
        float l0 = s0 * sc * invk[db + 0];
        float l1 = s1 * sc * invk[db + 1];
        float l2 = s2 * sc * invk[db + 2];
        float l3 = s3 * sc * invk[db + 3];
        float m = fmaxf(fmaxf(l0, l1), fmaxf(l2, l3));
        m = fmaxf(m, __shfl_xor(m, 1));
        m = fmaxf(m, __shfl_xor(m, 2));
        m = fmaxf(m, __shfl_xor(m, 4));
        const float e0 = expf(l0 - m), e1 = expf(l1 - m);
        const float e2 = expf(l2 - m), e3 = expf(l3 - m);
        float sum = e0 + e1 + e2 + e3;
        sum += __shfl_xor(sum, 1); sum += __shfl_xor(sum, 2); sum += __shfl_xor(sum, 4);
        const float inv = 1.f / sum;
        P[c][db + 0] = e0 * inv; P[c][db + 1] = e1 * inv;
        P[c][db + 2] = e2 * inv; P[c][db + 3] = e3 * inv;
    }
    __syncthreads();

    for (int idx = t; idx < 32 * nf4; idx += 256) {   // out = P @ v
        const int c  = idx / nf4;
        const int n4 = (idx % nf4) << 2;
        float4 o = make_float4(0.f, 0.f, 0.f, 0.f);
        #pragma unroll
        for (int d = 0; d < 32; ++d) {
            const float p = P[c][d];
            const float4 vv = *(const float4*)&vs[d][n4];
            o.x = fmaf(p, vv.x, o.x); o.y = fmaf(p, vv.y, o.y);
            o.z = fmaf(p, vv.z, o.z); o.w = fmaf(p, vv.w, o.w);
        }
        *(float4*)&O[base + (long)c * NTOK + n4] = o;
    }
}

// LayerNorm over the 512 channels per token; Pre/out are (B,512,320) channel-major.
__global__ __launch_bounds__(256)
void ln_kernel(const float* __restrict__ Pre, const float* __restrict__ gamma,
               const float* __restrict__ beta, float* __restrict__ out)
{
    const int b  = blockIdx.y;
    const int n  = (blockIdx.x << 6) + (threadIdx.x & 63);
    const int q  = threadIdx.x >> 6;   // 0..3
    const float* Pb = Pre + (long)b * DIMC * NTOK;
    float s = 0.f, s2 = 0.f;
    for (int d = q; d < DIMC; d += 4) {
        const float v = Pb[(long)d * NTOK + n];
        s += v; s2 = fmaf(v, v, s2);
    }
    __shared__ float sb[4][64], s2b[4][64];
    sb[q][threadIdx.x & 63] = s;
    s2b[q][threadIdx.x & 63] = s2;
    __syncthreads();
    float ts = 0.f, ts2 = 0.f;
    #pragma unroll
    for (int i = 0; i < 4; ++i) { ts += sb[i][threadIdx.x & 63]; ts2 += s2b[i][threadIdx.x & 63]; }
    const float mu   = ts * (1.f / 512.f);
    const float var  = ts2 * (1.f / 512.f) - mu * mu;
    const float rstd = 1.f / sqrtf(var + 1e-5f);
    float* Ob = out + (long)b * DIMC * NTOK;
    for (int d = q; d < DIMC; d += 4) {
        const float v = Pb[(long)d * NTOK + n];
        Ob[(long)d * NTOK + n] = (v - mu) * rstd * gamma[d] + beta[d];
    }
}

extern "C" void kernel_launch(void* const* d_in, const int* in_sizes, int n_in,
                              void* d_out, int out_size, void* d_ws, size_t ws_size,
                              hipStream_t stream)
{
    const float* x1     = (const float*)d_in[0];
    const float* x2     = (const float*)d_in[1];
    const float* W_lin  = (const float*)d_in[2];
    const float* b_lin  = (const float*)d_in[3];
    const float* W_down = (const float*)d_in[4];
    const float* b_down = (const float*)d_in[5];
    const float* W_up   = (const float*)d_in[6];
    const float* b_up   = (const float*)d_in[7];
    const float* Wq     = (const float*)d_in[8];
    const float* Wk     = (const float*)d_in[9];
    const float* Wv     = (const float*)d_in[10];
    const float* Wo     = (const float*)d_in[11];
    const float* temp   = (const float*)d_in[12];
    const float* W_end  = (const float*)d_in[13];
    const float* b_end  = (const float*)d_in[14];
    const float* gamma  = (const float*)d_in[15];
    const float* beta   = (const float*)d_in[16];

    float* ws = (float*)d_ws;
    const long s512  = (long)DIMC * NTOK;      // 163840
    const long s1024 = 2L * s512;
    const long s256  = (long)HIDC * NTOK;      // 81920

    float* H1  = ws;                               // B x 1024 x 320  (rows 0-511 = Y1, 512-1023 = U1)
    float* U2  = H1 + (long)BB * 1024 * NTOK;      // B x 512 x 320
    float* XB  = U2 + (long)BB * 512 * NTOK;       // B x 256 x 320
    float* YB  = XB + (long)BB * 256 * NTOK;
    float* Qb  = YB + (long)BB * 256 * NTOK;
    float* Kb  = Qb + (long)BB * 256 * NTOK;
    float* Vb  = Kb + (long)BB * 256 * NTOK;
    float* WT  = Vb + (long)BB * 256 * NTOK;       // 4 x 256 x 256 transposed proj weights
    float* Y1   = H1;                // stride s1024
    float* U1   = H1 + 512 * NTOK;   // stride s1024
    float* AO   = YB;                // alias: YB dead after Q projection
    float* OUTC = Qb;                // alias: Q dead after attention
    float* PRE  = U2;                // alias: U2 dead after YB projection

    const dim3 blk(256);

    transpose4_k<<<dim3(8, 8, 4), blk, 0, stream>>>(Wq, Wk, Wv, Wo, WT);

    // H1 = relu(W_lin^T @ X1 + b_lin)            (Y1 | U1)
    gemm_mfma<F_BIAS | F_RELU><<<dim3(8, 5, BB), blk, 0, stream>>>(
        W_lin, 1024, x1, s512, H1, s1024, 512, b_lin, nullptr, 0, nullptr, 0);
    // U2 = relu(W_lin[:,512:]^T @ X2 + b_lin[512:])
    gemm_mfma<F_BIAS | F_RELU><<<dim3(4, 5, BB), blk, 0, stream>>>(
        W_lin + 512, 1024, x2, s512, U2, s512, 512, b_lin + 512, nullptr, 0, nullptr, 0);
    // XB = relu(W_down^T @ U1 + b_down)   (== xb, the res1)
    gemm_mfma<F_BIAS | F_RELU><<<dim3(2, 5, BB), blk, 0, stream>>>(
        W_down, 256, U1, s1024, XB, s256, 512, b_down, nullptr, 0, nullptr, 0);
    // YB = relu(W_down^T @ U2 + b_down)   (== yb)
    gemm_mfma<F_BIAS | F_RELU><<<dim3(2, 5, BB), blk, 0, stream>>>(
        W_down, 256, U2, s512, YB, s256, 512, b_down, nullptr, 0, nullptr, 0);
    // Q = Wq @ YB ; K = Wk @ XB ; V = Wv @ XB   (via transposed weights)
    gemm_mfma<0><<<dim3(2, 5, BB), blk, 0, stream>>>(
        WT + 0 * 65536, 256, YB, s256, Qb, s256, 256, nullptr, nullptr, 0, nullptr, 0);
    gemm_mfma<0><<<dim3(2, 5, BB), blk, 0, stream>>>(
        WT + 1 * 65536, 256, XB, s256, Kb, s256, 256, nullptr, nullptr, 0, nullptr, 0);
    gemm_mfma<0><<<dim3(2, 5, BB), blk, 0, stream>>>(
        WT + 2 * 65536, 256, XB, s256, Vb, s256, 256, nullptr, nullptr, 0, nullptr, 0);
    // attention per (slice, head, batch) -> AO
    attn_kernel<<<dim3(2, NHEAD, BB), blk, 0, stream>>>(Qb, Kb, Vb, AO, temp);
    // OUTC = Wo @ AO + XB   (res1)
    gemm_mfma<F_RES1><<<dim3(2, 5, BB), blk, 0, stream>>>(
        WT + 3 * 65536, 256, AO, s256, OUTC, s256, 256, nullptr, XB, s256, nullptr, 0);
    // Y1 <- Y1 + U1 + W_up^T @ OUTC + b_up      (= y1 + branch outputs)
    gemm_mfma<F_BIAS | F_RES1 | F_RES2><<<dim3(4, 5, BB), blk, 0, stream>>>(
        W_up, 512, OUTC, s256, Y1, s1024, 256, b_up, U1, s1024, Y1, s1024);
    // PRE = x1 + W_end^T @ Y1 + b_end
    gemm_mfma<F_BIAS | F_RES1><<<dim3(4, 5, BB), blk, 0, stream>>>(
        W_end, 512, Y1, s1024, PRE, s512, 512, b_end, x1, s512, nullptr, 0);
    // LayerNorm over channels -> d_out (already channel-major == output layout)
    ln_kernel<<<dim3(5, BB), blk, 0, stream>>>(PRE, gamma, beta, (float*)d_out);
}